// Round 1
// baseline (424.372 us; speedup 1.0000x reference)
//
#include <hip/hip_runtime.h>
#include <hip/hip_bf16.h>

// ---------------- problem constants ----------------
constexpr int N_NODE = 4096;
constexpr int DIM    = 512;
constexpr int HID    = 256;
constexpr int NCLS   = 32;
constexpr int N_EDGE = 131072;
constexpr float ALPHA_C = 0.85f;
constexpr float EPS_C   = 1e-8f;
constexpr int N_ITER_SPMV = 49;   // + 1 init application = 50 total; err <= 0.85^50 * max|L|

// ---------------- workspace layout (bytes) ----------------
// zeroed region (one memsetAsync): [0, 0x208200)
constexpr size_t OFF_BITMAP  = 0x000000;  // 2 MB   (4096*4096 bits) dedup
constexpr size_t OFF_ROWCNT  = 0x200000;  // 16 KB  per-row nnz count
constexpr size_t OFF_DIAGEX  = 0x204000;  // 16 KB  self-loop exists flag
constexpr size_t OFF_CNT     = 0x208000;  // counters: [0]=nnz, flags at [4],[5]
constexpr size_t ZERO_BYTES  = 0x208200;
// non-zeroed
constexpr size_t OFF_LOGITS  = 0x210000;  // 512 KB
constexpr size_t OFF_F       = 0x290000;  // 512 KB (normalized logits)
constexpr size_t OFF_DIAGSIM = 0x310000;  // 16 KB
constexpr size_t OFF_ROWPTR  = 0x314000;  // 4097 ints
constexpr size_t OFF_ROWNEXT = 0x31C000;  // 16 KB
constexpr size_t OFF_TR_R    = 0x320000;  // 512 KB
constexpr size_t OFF_TR_C    = 0x3A0000;  // 512 KB
constexpr size_t OFF_TR_V    = 0x420000;  // 512 KB
constexpr size_t OFF_CSRCOL  = 0x4A0000;  // 512 KB
constexpr size_t OFF_CSRVAL  = 0x520000;  // 512 KB
constexpr size_t OFF_PDIAG   = 0x5A0000;  // 16 KB  (alpha * P diagonal)
constexpr size_t OFF_BUFA    = 0x5A4000;  // 512 KB
constexpr size_t OFF_BUFB    = 0x624000;  // 512 KB

// ---------------- K1: MLP + logits + normalized f ----------------
// 8 nodes per block, 256 threads. fp32 throughout (threshold semantics are
// fragile under bf16: sims near 0.1 would flip).
constexpr int NPB = 8;
__global__ __launch_bounds__(256) void mlp_kernel(
    const float* __restrict__ attr, const float* __restrict__ W0,
    const float* __restrict__ b0, const float* __restrict__ W1,
    const float* __restrict__ b1, float* __restrict__ logits,
    float* __restrict__ f)
{
    __shared__ float attr_s[NPB * DIM];   // 16 KB
    __shared__ float x_s[NPB * HID];      // 8 KB
    const int t = threadIdx.x;
    const int node0 = blockIdx.x * NPB;
    const float* ap = attr + (size_t)node0 * DIM;
    for (int i = t; i < NPB * DIM; i += 256) attr_s[i] = ap[i];
    __syncthreads();

    // hidden layer: thread t = hidden unit t, for all 8 nodes
    float acc[NPB];
    float bb = b0[t];
#pragma unroll
    for (int n = 0; n < NPB; n++) acc[n] = bb;
#pragma unroll 8
    for (int k = 0; k < DIM; k++) {
        float w = W0[k * HID + t];
#pragma unroll
        for (int n = 0; n < NPB; n++)
            acc[n] = fmaf(attr_s[n * DIM + k], w, acc[n]);
    }
#pragma unroll
    for (int n = 0; n < NPB; n++) x_s[n * HID + t] = fmaxf(acc[n], 0.0f);
    __syncthreads();

    // output layer: thread t -> node t>>5, class t&31
    const int n = t >> 5, c = t & 31;
    float lg = b1[c];
#pragma unroll 8
    for (int k = 0; k < HID; k++)
        lg = fmaf(x_s[n * HID + k], W1[k * NCLS + c], lg);

    // row norm across the 32 class lanes
    float sq = lg * lg;
#pragma unroll
    for (int m = 16; m >= 1; m >>= 1) sq += __shfl_xor(sq, m, 32);
    float nr = fmaxf(sqrtf(sq), EPS_C);
    const int r = node0 + n;
    logits[r * NCLS + c] = lg;
    f[r * NCLS + c] = lg / nr;
}

// ---------------- K2: edge sims + dedup + row counts ----------------
__global__ __launch_bounds__(256) void edge_kernel(
    const int* __restrict__ row, const int* __restrict__ col,
    const float* __restrict__ f, unsigned int* __restrict__ bitmap,
    int* __restrict__ row_count, int* __restrict__ tr_r,
    int* __restrict__ tr_c, float* __restrict__ tr_v,
    float* __restrict__ diag_sim, int* __restrict__ diag_ex,
    int* __restrict__ nnz_counter)
{
    const int e = blockIdx.x * blockDim.x + threadIdx.x;
    if (e >= N_EDGE) return;
    const int r = row[e], c = col[e];
    const float4* fr = (const float4*)(f + r * NCLS);
    const float4* fc = (const float4*)(f + c * NCLS);
    float sim = 0.f;
#pragma unroll
    for (int q = 0; q < 8; q++) {
        float4 a = fr[q], b = fc[q];
        sim += a.x * b.x + a.y * b.y + a.z * b.z + a.w * b.w;
    }
    if (sim < 0.1f) return;  // where(sim<0.1, 0, sim): zero == absent cell
    if (r == c) {
        // self-loop: route to diag arrays (dup writes are identical values)
        diag_ex[r] = 1;
        diag_sim[r] = sim;
    } else {
        // dedup: .at[r,c].set counts a cell ONCE even with duplicate edges
        unsigned int bit = (unsigned int)r * N_NODE + (unsigned int)c;
        unsigned int w = bit >> 5, m = 1u << (bit & 31);
        unsigned int old = atomicOr(&bitmap[w], m);
        if (!(old & m)) {
            int idx = atomicAdd(nnz_counter, 1);
            tr_r[idx] = r; tr_c[idx] = c; tr_v[idx] = sim;
            atomicAdd(&row_count[r], 1);
        }
    }
}

// ---------------- K3: exclusive prefix scan of 4096 row counts ----------------
__global__ __launch_bounds__(1024) void scan_kernel(
    const int* __restrict__ row_count, int* __restrict__ row_ptr,
    int* __restrict__ row_next)
{
    __shared__ int s[1024];
    const int t = threadIdx.x;
    int v0 = row_count[t * 4 + 0], v1 = row_count[t * 4 + 1];
    int v2 = row_count[t * 4 + 2], v3 = row_count[t * 4 + 3];
    int sum = v0 + v1 + v2 + v3;
    s[t] = sum;
    __syncthreads();
    for (int off = 1; off < 1024; off <<= 1) {
        int x = (t >= off) ? s[t - off] : 0;
        __syncthreads();
        s[t] += x;
        __syncthreads();
    }
    int excl = s[t] - sum;
    row_ptr[t * 4 + 0] = excl; row_next[t * 4 + 0] = excl; excl += v0;
    row_ptr[t * 4 + 1] = excl; row_next[t * 4 + 1] = excl; excl += v1;
    row_ptr[t * 4 + 2] = excl; row_next[t * 4 + 2] = excl; excl += v2;
    row_ptr[t * 4 + 3] = excl; row_next[t * 4 + 3] = excl; excl += v3;
    if (t == 1023) row_ptr[4096] = s[1023];
}

// ---------------- K4: scatter triples into CSR ----------------
__global__ __launch_bounds__(256) void scatter_kernel(
    const int* __restrict__ tr_r, const int* __restrict__ tr_c,
    const float* __restrict__ tr_v, const int* __restrict__ nnz_counter,
    int* __restrict__ row_next, int* __restrict__ csr_col,
    float* __restrict__ csr_val)
{
    const int i = blockIdx.x * blockDim.x + threadIdx.x;
    if (i >= nnz_counter[0]) return;
    const int r = tr_r[i];
    int pos = atomicAdd(&row_next[r], 1);
    csr_col[pos] = tr_c[i];
    csr_val[pos] = tr_v[i];
}

// ---------------- K5: data-dependent global flags ----------------
__global__ void flags_kernel(const int* __restrict__ diag_ex,
                             const float* __restrict__ diag_sim,
                             int* __restrict__ flags)
{
    if (threadIdx.x == 0 && blockIdx.x == 0) {
        float S00 = diag_ex[0] ? diag_sim[0] : 0.0f;
        int rm = (S00 == 1.0f) ? 1 : 0;          // remove diagonal?
        float d_eff0 = rm ? 0.0f : S00;
        int add = (d_eff0 == 0.0f) ? 1 : 0;      // add diag(lam)?
        flags[0] = rm;
        flags[1] = add;
    }
}

// ---------------- K6: per-row normalize + exp + build alpha*P ----------------
// One 64-lane wave per row: coalesced loads + shuffle reductions.
// (Was one thread per row with 3 serial ~32-iteration loops on 64 waves total.)
__global__ __launch_bounds__(256) void finalize_kernel(
    const int* __restrict__ row_ptr, float* __restrict__ csr_val,
    const int* __restrict__ diag_ex, const float* __restrict__ diag_sim,
    const int* __restrict__ flags, float* __restrict__ pdiag)
{
    const int t = threadIdx.x;
    const int lane = t & 63;
    const int r = blockIdx.x * 4 + (t >> 6);   // 4 rows (waves) per block
    const int rm = flags[0], add = flags[1];
    const int s = row_ptr[r], e = row_ptr[r + 1];
    const int len = e - s;
    float d = diag_ex[r] ? diag_sim[r] : 0.0f;
    float d_eff = rm ? 0.0f : d;

    // L1 rowsum (all surviving vals >= 0.1 > 0)
    float part = 0.0f;
    for (int j = lane; j < len; j += 64) part += csr_val[s + j];
#pragma unroll
    for (int m = 32; m >= 1; m >>= 1) part += __shfl_xor(part, m, 64);
    float rowsum = d_eff + part;
    float denom = (rowsum == 0.0f) ? 1.0f : rowsum;
    float sn_d = d_eff / denom;
    int degree = len + ((sn_d != 0.0f) ? 1 : 0);  // count(Sn != 0)
    float lam = 1.0f / (float)(degree + 1);
    float diag_final = sn_d + (add ? lam : 0.0f);
    float a_d = (diag_final != 0.0f) ? expf(diag_final) : 0.0f;  // exp on nz pattern

    float epart = 0.0f;
    for (int j = lane; j < len; j += 64) epart += expf(csr_val[s + j] / denom);
#pragma unroll
    for (int m = 32; m >= 1; m >>= 1) epart += __shfl_xor(epart, m, 64);
    float degA = a_d + epart;
    float inv = 1.0f / fmaxf(degA, EPS_C);
    if (lane == 0) pdiag[r] = ALPHA_C * a_d * inv;
    for (int j = lane; j < len; j += 64)
        csr_val[s + j] = ALPHA_C * expf(csr_val[s + j] / denom) * inv;
}

// ---------------- K7: Y1 = (1-alpha) * L ----------------
__global__ __launch_bounds__(256) void init_kernel(
    const float* __restrict__ logits, float* __restrict__ Y)
{
    const int i = blockIdx.x * blockDim.x + threadIdx.x;
    Y[i] = (1.0f - ALPHA_C) * logits[i];
}

// ---------------- K8: Y_out = (1-a)L + aP * Y_in  (32 RHS) ----------------
// One row per 64-lane wave. Lane l = (half h = l>>5, class c = l&31).
// Cols/vals for the row are loaded ONCE coalesced (lane l takes entry l of
// the chunk), then broadcast via register shuffles so the Yin gathers have
// no memory-latency dependency on their address source and can all be in
// flight at once. Half 0 accumulates entries 0..31 of each 64-chunk, half 1
// entries 32..63; combined with one shfl_xor(32). Avg degree ~32 -> the
// chunk loop runs once for almost every row.
__global__ __launch_bounds__(256) void spmv_kernel(
    const float* __restrict__ Yin, const float* __restrict__ logits,
    const int* __restrict__ row_ptr, const int* __restrict__ csr_col,
    const float* __restrict__ csr_val, const float* __restrict__ pdiag,
    float* __restrict__ Yout)
{
    const int t = threadIdx.x;
    const int lane = t & 63;
    const int r = blockIdx.x * 4 + (t >> 6);   // 4 rows (waves) per block
    const int c = lane & 31;
    const int h = lane >> 5;
    const int s = row_ptr[r], e = row_ptr[r + 1];
    const int len = e - s;

    float acc = 0.0f;
    if (h == 0)
        acc = fmaf(pdiag[r], Yin[r * NCLS + c],
                   (1.0f - ALPHA_C) * logits[r * NCLS + c]);

    for (int j0 = 0; j0 < len; j0 += 64) {
        const int myj = j0 + lane;
        const bool ok = myj < len;
        int   cj = ok ? csr_col[s + myj] : 0;
        float vj = ok ? csr_val[s + myj] : 0.0f;   // vv=0 => masked fma adds 0
#pragma unroll 16
        for (int j = 0; j < 32; j++) {
            int   cc = __shfl(cj, j, 32);
            float vv = __shfl(vj, j, 32);
            acc = fmaf(vv, Yin[cc * NCLS + c], acc);
        }
    }
    acc += __shfl_xor(acc, 32, 64);
    if (h == 0) Yout[r * NCLS + c] = acc;
}

// ---------------- launch ----------------
extern "C" void kernel_launch(void* const* d_in, const int* in_sizes, int n_in,
                              void* d_out, int out_size, void* d_ws, size_t ws_size,
                              hipStream_t stream)
{
    const float* attr = (const float*)d_in[0];
    const int*   row  = (const int*)d_in[1];
    const int*   col  = (const int*)d_in[2];
    const float* W0   = (const float*)d_in[3];
    const float* b0   = (const float*)d_in[4];
    const float* W1   = (const float*)d_in[5];
    const float* b1   = (const float*)d_in[6];
    float* out = (float*)d_out;

    char* ws = (char*)d_ws;
    unsigned int* bitmap   = (unsigned int*)(ws + OFF_BITMAP);
    int*   row_count = (int*)(ws + OFF_ROWCNT);
    int*   diag_ex   = (int*)(ws + OFF_DIAGEX);
    int*   cnt       = (int*)(ws + OFF_CNT);      // [0]=nnz
    int*   flags     = cnt + 4;                    // [0]=rm, [1]=add
    float* logits    = (float*)(ws + OFF_LOGITS);
    float* f         = (float*)(ws + OFF_F);
    float* diag_sim  = (float*)(ws + OFF_DIAGSIM);
    int*   row_ptr   = (int*)(ws + OFF_ROWPTR);
    int*   row_next  = (int*)(ws + OFF_ROWNEXT);
    int*   tr_r      = (int*)(ws + OFF_TR_R);
    int*   tr_c      = (int*)(ws + OFF_TR_C);
    float* tr_v      = (float*)(ws + OFF_TR_V);
    int*   csr_col   = (int*)(ws + OFF_CSRCOL);
    float* csr_val   = (float*)(ws + OFF_CSRVAL);
    float* pdiag     = (float*)(ws + OFF_PDIAG);
    float* bufA      = (float*)(ws + OFF_BUFA);
    float* bufB      = (float*)(ws + OFF_BUFB);

    hipMemsetAsync(ws, 0, ZERO_BYTES, stream);

    mlp_kernel<<<N_NODE / NPB, 256, 0, stream>>>(attr, W0, b0, W1, b1, logits, f);
    edge_kernel<<<N_EDGE / 256, 256, 0, stream>>>(row, col, f, bitmap, row_count,
                                                  tr_r, tr_c, tr_v, diag_sim,
                                                  diag_ex, cnt);
    scan_kernel<<<1, 1024, 0, stream>>>(row_count, row_ptr, row_next);
    scatter_kernel<<<N_EDGE / 256, 256, 0, stream>>>(tr_r, tr_c, tr_v, cnt,
                                                     row_next, csr_col, csr_val);
    flags_kernel<<<1, 64, 0, stream>>>(diag_ex, diag_sim, flags);
    finalize_kernel<<<N_NODE / 4, 256, 0, stream>>>(row_ptr, csr_val, diag_ex,
                                                    diag_sim, flags, pdiag);
    init_kernel<<<(N_NODE * NCLS) / 256, 256, 0, stream>>>(logits, bufA);

    for (int i = 0; i < N_ITER_SPMV; i++) {
        const float* src = (i & 1) ? bufB : bufA;
        float* dst = (i == N_ITER_SPMV - 1) ? out : ((i & 1) ? bufA : bufB);
        spmv_kernel<<<N_NODE / 4, 256, 0, stream>>>(src, logits, row_ptr, csr_col,
                                                    csr_val, pdiag, dst);
    }
}